// Round 6
// baseline (254.067 us; speedup 1.0000x reference)
//
#include <hip/hip_runtime.h>

typedef _Float16 f16;
typedef _Float16 f16x8 __attribute__((ext_vector_type(8)));
typedef float f32x4 __attribute__((ext_vector_type(4)));

// async global->LDS, 16B per lane; LDS dest = wave-uniform base + lane*16
#define GLD16(g, l) __builtin_amdgcn_global_load_lds( \
    (const __attribute__((address_space(1))) void*)(g), \
    (__attribute__((address_space(3))) void*)(l), 16, 0, 0)

// ---------------------------------------------------------------------------
// Generic f16 MFMA GEMM, BK=64: C[m][n] = sum_k A[m][k]*B[n][k] (+bias)
// A: [M][K] f16 row-major, B: [N][K] f16 row-major (B^T layout).
// MODE: 0 none, 1 bias[col], 4 = QKV split: col<768 -> C (Q,+bias),
//       col<1536 -> C2 (K,+bias2), else -> C3 = VT TRANSPOSED (+bias3):
//       C3[(row>>11)*768*2048 + cc*2048 + (row&2047)].
// 256 threads = 4 waves (2x2); wave tile (BM/2)x(BN/2); MFMA 16x16x32_f16,
// two k-groups per K-step. Two-barrier single-buffer K-loop (graph-replay-
// safe; single-barrier dbuf raced in R3). LDS row = 64 f16 = 128 B; XOR
// swizzle: slot s of row r holds global chunk s^(r&7) -> ds_read_b128
// bank-conflict-free (R5: SQ_LDS_BANK_CONFLICT = 0).
// Wave-tile sizing: 64x64 reads 16KB LDS / 154 MFMA-cyc per K=64 (mildly
// LDS-bound); 64x128 is balanced; avoid 64x32 (2:1 LDS-bound).
// ---------------------------------------------------------------------------
template <typename OutT, int BM, int BN, int MODE, int MINW>
__global__ __launch_bounds__(256, MINW)
void gemm_kernel(const f16* __restrict__ A, long sA,
                 const f16* __restrict__ B, long sB,
                 void* __restrict__ Cv, long sC,
                 void* __restrict__ C2v, void* __restrict__ C3v,
                 const float* __restrict__ bias,
                 const float* __restrict__ bias2,
                 const float* __restrict__ bias3,
                 int N, int K)
{
    constexpr int FM = BM / 32;   // A-frags per wave
    constexpr int FN = BN / 32;
    constexpr int IA = BM / 32;   // staging issues per wave (8 rows each)
    constexpr int IB = BN / 32;

    OutT* C  = (OutT*)Cv;
    const int tid  = threadIdx.x;
    const int wave = tid >> 6;
    const int lane = tid & 63;
    const int bz   = blockIdx.z;
    A += (long)bz * sA;
    B += (long)bz * sB;
    C += (long)bz * sC;
    const long bm = (long)blockIdx.x * BM;
    const long bn = (long)blockIdx.y * BN;

    __shared__ f16 sAt[BM * 64];
    __shared__ f16 sBt[BN * 64];

    // staging lane map: row = lane>>3, slot = lane&7, source chunk slot^row
    const int srow = lane >> 3;
    const int gch  = ((lane & 7) ^ srow) * 8;

    const f16* gAb = A + (bm + wave * (BM / 4) + srow) * (long)K + gch;
    const f16* gBb = B + (bn + wave * (BN / 4) + srow) * (long)K + gch;

    const int wm = (wave >> 1) * (BM / 2);
    const int wn = (wave & 1) * (BN / 2);
    const int lr = lane & 15;
    const int qd = lane >> 4;
    // reader swizzle per k-group h: slot = (h*4+qd) ^ (lr&7)
    const int swz0 = ((0 * 4 + qd) ^ (lr & 7)) * 8;
    const int swz1 = ((1 * 4 + qd) ^ (lr & 7)) * 8;

    f32x4 acc[FM][FN] = {};

    for (int k0 = 0; k0 < K; k0 += 64) {
        #pragma unroll
        for (int i = 0; i < IA; ++i)
            GLD16(gAb + k0 + (long)i * 8 * K, &sAt[(wave * (BM / 4) + i * 8) * 64]);
        #pragma unroll
        for (int i = 0; i < IB; ++i)
            GLD16(gBb + k0 + (long)i * 8 * K, &sBt[(wave * (BN / 4) + i * 8) * 64]);
        __syncthreads();

        #pragma unroll
        for (int h = 0; h < 2; ++h) {
            const int swz = h ? swz1 : swz0;
            f16x8 af[FM], bf[FN];
            #pragma unroll
            for (int t = 0; t < FM; ++t)
                af[t] = *(const f16x8*)&sAt[(wm + t * 16 + lr) * 64 + swz];
            #pragma unroll
            for (int t = 0; t < FN; ++t)
                bf[t] = *(const f16x8*)&sBt[(wn + t * 16 + lr) * 64 + swz];
            #pragma unroll
            for (int tm = 0; tm < FM; ++tm)
                #pragma unroll
                for (int tn = 0; tn < FN; ++tn)
                    acc[tm][tn] = __builtin_amdgcn_mfma_f32_16x16x32_f16(
                        af[tm], bf[tn], acc[tm][tn], 0, 0, 0);
        }
        __syncthreads();
    }

    // epilogue: C/D layout col = lane&15, row = (lane>>4)*4 + reg
    #pragma unroll
    for (int tn = 0; tn < FN; ++tn) {
        const long col = bn + wn + tn * 16 + lr;
        if (MODE == 4) {
            // region is uniform over the 16-col group (768 % 16 == 0)
            const int  region = (int)(col >> 8) / 3;     // col/768
            const long cc = col - (long)region * 768;
            const float bc = (region == 0) ? bias[cc]
                           : (region == 1) ? bias2[cc] : bias3[cc];
            #pragma unroll
            for (int tm = 0; tm < FM; ++tm) {
                #pragma unroll
                for (int r = 0; r < 4; ++r) {
                    const long row = bm + wm + tm * 16 + qd * 4 + r;
                    const float v = acc[tm][tn][r] + bc;
                    if (region == 0)
                        ((f16*)Cv)[row * 768 + cc] = (f16)v;
                    else if (region == 1)
                        ((f16*)C2v)[row * 768 + cc] = (f16)v;
                    else
                        ((f16*)C3v)[(row >> 11) * (768L * 2048) + cc * 2048
                                    + (row & 2047)] = (f16)v;
                }
            }
        } else {
            const float bc = (MODE == 1) ? bias[col] : 0.f;
            #pragma unroll
            for (int tm = 0; tm < FM; ++tm) {
                #pragma unroll
                for (int r = 0; r < 4; ++r) {
                    const long row = bm + wm + tm * 16 + qd * 4 + r;
                    C[row * (long)N + col] = (OutT)(acc[tm][tn][r] + bc);
                }
            }
        }
    }
}

// ---------------------------------------------------------------------------
// In-place row softmax over f16 scores; one block per row of 2048.
// fp32 math, unscaled (faithful to reference). Proven in R1/R2/R5.
// ---------------------------------------------------------------------------
__global__ __launch_bounds__(256)
void softmax_kernel(f16* __restrict__ S)
{
    const long row = blockIdx.x;
    f16* p = S + row * 2048;
    const int tid  = threadIdx.x;
    const int wave = tid >> 6;
    const int lane = tid & 63;

    f16x8 x = *(const f16x8*)&p[tid * 8];
    float v[8];
    float m = -1e30f;
    #pragma unroll
    for (int j = 0; j < 8; ++j) { v[j] = (float)x[j]; m = fmaxf(m, v[j]); }
    #pragma unroll
    for (int off = 32; off > 0; off >>= 1) m = fmaxf(m, __shfl_down(m, off));

    __shared__ float rm[4], rs[4];
    if (lane == 0) rm[wave] = m;
    __syncthreads();
    m = fmaxf(fmaxf(rm[0], rm[1]), fmaxf(rm[2], rm[3]));

    float s = 0.f;
    #pragma unroll
    for (int j = 0; j < 8; ++j) { v[j] = __expf(v[j] - m); s += v[j]; }
    #pragma unroll
    for (int off = 32; off > 0; off >>= 1) s += __shfl_down(s, off);
    if (lane == 0) rs[wave] = s;
    __syncthreads();
    s = rs[0] + rs[1] + rs[2] + rs[3];
    const float inv = 1.0f / s;

    f16x8 y;
    #pragma unroll
    for (int j = 0; j < 8; ++j) y[j] = (f16)(v[j] * inv);
    *(f16x8*)&p[tid * 8] = y;
}

// ---------------------------------------------------------------------------
// fused fp32 -> f16 convert: blocks [0,3072) do x (6.29M elems),
// blocks [3072, 4224) do the 4 weight matrices (589824 elems each).
// ---------------------------------------------------------------------------
__global__ __launch_bounds__(256)
void cvt_all_kernel(const float* __restrict__ x,
                    const float* __restrict__ w0, const float* __restrict__ w1,
                    const float* __restrict__ w2, const float* __restrict__ w3,
                    f16* __restrict__ x16, f16* __restrict__ w16)
{
    const float* in; f16* out; long i;
    if (blockIdx.x < 3072) {
        in = x; out = x16;
        i = ((long)blockIdx.x * 256 + threadIdx.x) * 8;
    } else {
        const int wb  = blockIdx.x - 3072;          // 0..1151
        const int sel = wb / 288;                   // 288 blocks per weight
        in  = (sel == 0) ? w0 : (sel == 1) ? w1 : (sel == 2) ? w2 : w3;
        out = w16 + (long)sel * 589824;
        i = ((long)(wb - sel * 288) * 256 + threadIdx.x) * 8;
    }
    float4 a = *(const float4*)(in + i);
    float4 b = *(const float4*)(in + i + 4);
    f16x8 o;
    o[0] = (f16)a.x; o[1] = (f16)a.y; o[2] = (f16)a.z; o[3] = (f16)a.w;
    o[4] = (f16)b.x; o[5] = (f16)b.y; o[6] = (f16)b.z; o[7] = (f16)b.w;
    *(f16x8*)&out[i] = o;
}

// ---------------------------------------------------------------------------
// B=4, S=2048, D=H=768.  ws layout (bytes):
//   x16 @0  (12.6MB) | w16 @12582912 (4.7MB: wq,wk,wv,wo) | Q @17301504
//   K @29884416 | VT @42467328 ([4][768][2048]) | S @55050240 (33.5MB)
//   Y @88604672      total ~101 MB
// ---------------------------------------------------------------------------
extern "C" void kernel_launch(void* const* d_in, const int* in_sizes, int n_in,
                              void* d_out, int out_size, void* d_ws, size_t ws_size,
                              hipStream_t stream)
{
    const float* x  = (const float*)d_in[0];
    const float* wq = (const float*)d_in[1];
    const float* bq = (const float*)d_in[2];
    const float* wk = (const float*)d_in[3];
    const float* bk = (const float*)d_in[4];
    const float* wv = (const float*)d_in[5];
    const float* bv = (const float*)d_in[6];
    const float* wo = (const float*)d_in[7];
    const float* bo = (const float*)d_in[8];

    char* ws = (char*)d_ws;
    f16* x16 = (f16*)(ws + 0);
    f16* w16 = (f16*)(ws + 12582912);
    f16* Q   = (f16*)(ws + 17301504);
    f16* Kb  = (f16*)(ws + 29884416);
    f16* VT  = (f16*)(ws + 42467328);
    f16* S   = (f16*)(ws + 55050240);
    f16* Y   = (f16*)(ws + 88604672);

    f16* wo16 = w16 + 3 * 589824;

    cvt_all_kernel<<<4224, 256, 0, stream>>>(x, wq, wk, wv, wo, x16, w16);

    // fused Q|K|V projection: B = [wq;wk;wv] (contiguous in w16), N=2304.
    // Epilogue splits: Q, K row-major; V written transposed into VT.
    gemm_kernel<f16, 128, 256, 4, 2><<<dim3(64, 9, 1), 256, 0, stream>>>(
        x16, 0, w16, 0, Q, 0, Kb, VT, bq, bk, bv, 2304, 768);
    // S[b] = Q[b] @ K[b]^T  (128x256 tiles, 512 blocks = 2/CU)
    gemm_kernel<f16, 128, 256, 0, 2><<<dim3(16, 8, 4), 256, 0, stream>>>(
        Q, (long)2048 * 768, Kb, (long)2048 * 768, S, (long)2048 * 2048,
        nullptr, nullptr, nullptr, nullptr, nullptr, 2048, 768);
    softmax_kernel<<<8192, 256, 0, stream>>>(S);
    // Y[b] = P[b] @ V[b]: A = S, B = VT  (128x128 tiles, 384 blocks, K=2048)
    gemm_kernel<f16, 128, 128, 0, 3><<<dim3(16, 6, 4), 256, 0, stream>>>(
        S, (long)2048 * 2048, VT, (long)768 * 2048, Y, (long)2048 * 768,
        nullptr, nullptr, nullptr, nullptr, nullptr, 768, 2048);
    // out = Y @ wo^T + bo (fp32 out, 128x128 tiles, 384 blocks)
    gemm_kernel<float, 128, 128, 1, 3><<<dim3(64, 6, 1), 256, 0, stream>>>(
        Y, 0, wo16, 0, (float*)d_out, 0, nullptr, nullptr, bo, nullptr,
        nullptr, 768, 768);
}

// Round 7
// 241.525 us; speedup vs baseline: 1.0519x; 1.0519x over previous
//
#include <hip/hip_runtime.h>

typedef _Float16 f16;
typedef _Float16 f16x8 __attribute__((ext_vector_type(8)));
typedef float f32x4 __attribute__((ext_vector_type(4)));

// async global->LDS, 16B per lane; LDS dest = wave-uniform base + lane*16
#define GLD16(g, l) __builtin_amdgcn_global_load_lds( \
    (const __attribute__((address_space(1))) void*)(g), \
    (__attribute__((address_space(3))) void*)(l), 16, 0, 0)

// ---------------------------------------------------------------------------
// Generic f16 MFMA GEMM, BK=64: C[m][n] = sum_k A[m][k]*B[n][k] (+bias)
// A: [M][K] f16 row-major, B: [N][K] f16 row-major (B^T layout).
// MODE: 0 none, 1 bias[col], 2 bias[row], 3 split-QK (col<768 -> C else C2).
// 256 threads = 4 waves (2x2); wave tile (BM/2)x(BN/2); MFMA 16x16x32_f16,
// two k-groups per K-step. Two-barrier single-buffer K-loop (graph-replay-
// safe; single-barrier dbuf raced in R3). LDS row = 64 f16 = 128 B; XOR
// swizzle: slot s of row r holds global chunk s^(r&7) -> ds_read_b128
// bank-conflict-free (R5/R6: SQ_LDS_BANK_CONFLICT = 0).
// Wave-tile sizing: 64x64 reads 16KB LDS / 154 MFMA-cyc per K=64 (mildly
// LDS-bound); 64x128 balanced; avoid 64x32 (2:1 LDS-bound).
// NOTE (R6 lesson): epilogues must write row-major/coalesced — the
// transposed-V epilogue cost +24 MB write amplification. Produce transposed
// operands via swapped-operand GEMMs instead.
// ---------------------------------------------------------------------------
template <typename OutT, int BM, int BN, int MODE, int MINW>
__global__ __launch_bounds__(256, MINW)
void gemm_kernel(const f16* __restrict__ A, long sA,
                 const f16* __restrict__ B, long sB,
                 void* __restrict__ Cv, long sC,
                 void* __restrict__ C2v,
                 const float* __restrict__ bias,
                 const float* __restrict__ bias2,
                 int N, int K)
{
    constexpr int FM = BM / 32;   // A-frags per wave
    constexpr int FN = BN / 32;
    constexpr int IA = BM / 32;   // staging issues per wave (8 rows each)
    constexpr int IB = BN / 32;

    OutT* C  = (OutT*)Cv;
    OutT* C2 = (OutT*)C2v;
    const int tid  = threadIdx.x;
    const int wave = tid >> 6;
    const int lane = tid & 63;
    const int bz   = blockIdx.z;
    A += (long)bz * sA;
    B += (long)bz * sB;
    C += (long)bz * sC;
    const long bm = (long)blockIdx.x * BM;
    const long bn = (long)blockIdx.y * BN;

    __shared__ f16 sAt[BM * 64];
    __shared__ f16 sBt[BN * 64];

    // staging lane map: row = lane>>3, slot = lane&7, source chunk slot^row
    const int srow = lane >> 3;
    const int gch  = ((lane & 7) ^ srow) * 8;

    const f16* gAb = A + (bm + wave * (BM / 4) + srow) * (long)K + gch;
    const f16* gBb = B + (bn + wave * (BN / 4) + srow) * (long)K + gch;

    const int wm = (wave >> 1) * (BM / 2);
    const int wn = (wave & 1) * (BN / 2);
    const int lr = lane & 15;
    const int qd = lane >> 4;
    // reader swizzle per k-group h: slot = (h*4+qd) ^ (lr&7)
    const int swz0 = ((0 * 4 + qd) ^ (lr & 7)) * 8;
    const int swz1 = ((1 * 4 + qd) ^ (lr & 7)) * 8;

    f32x4 acc[FM][FN] = {};

    for (int k0 = 0; k0 < K; k0 += 64) {
        #pragma unroll
        for (int i = 0; i < IA; ++i)
            GLD16(gAb + k0 + (long)i * 8 * K, &sAt[(wave * (BM / 4) + i * 8) * 64]);
        #pragma unroll
        for (int i = 0; i < IB; ++i)
            GLD16(gBb + k0 + (long)i * 8 * K, &sBt[(wave * (BN / 4) + i * 8) * 64]);
        __syncthreads();

        #pragma unroll
        for (int h = 0; h < 2; ++h) {
            const int swz = h ? swz1 : swz0;
            f16x8 af[FM], bf[FN];
            #pragma unroll
            for (int t = 0; t < FM; ++t)
                af[t] = *(const f16x8*)&sAt[(wm + t * 16 + lr) * 64 + swz];
            #pragma unroll
            for (int t = 0; t < FN; ++t)
                bf[t] = *(const f16x8*)&sBt[(wn + t * 16 + lr) * 64 + swz];
            #pragma unroll
            for (int tm = 0; tm < FM; ++tm)
                #pragma unroll
                for (int tn = 0; tn < FN; ++tn)
                    acc[tm][tn] = __builtin_amdgcn_mfma_f32_16x16x32_f16(
                        af[tm], bf[tn], acc[tm][tn], 0, 0, 0);
        }
        __syncthreads();
    }

    // epilogue: C/D layout col = lane&15, row = (lane>>4)*4 + reg
    #pragma unroll
    for (int tn = 0; tn < FN; ++tn) {
        const long col = bn + wn + tn * 16 + lr;
        OutT* dst = C;
        long cc = col, stride = N;
        float bc = 0.f;
        if (MODE == 1) bc = bias[col];
        if (MODE == 3) {
            stride = 768;
            if (col >= 768) { dst = C2; cc = col - 768; bc = bias2[cc]; }
            else            { bc = bias[cc]; }
        }
        #pragma unroll
        for (int tm = 0; tm < FM; ++tm) {
            #pragma unroll
            for (int r = 0; r < 4; ++r) {
                const long row = bm + wm + tm * 16 + qd * 4 + r;
                float v = acc[tm][tn][r] + bc;
                if (MODE == 2) v += bias[row];
                dst[row * stride + cc] = (OutT)v;
            }
        }
    }
}

// ---------------------------------------------------------------------------
// In-place row softmax over f16 scores; one block per row of 2048.
// fp32 math, unscaled (faithful to reference). Proven in R1/R2/R5.
// ---------------------------------------------------------------------------
__global__ __launch_bounds__(256)
void softmax_kernel(f16* __restrict__ S)
{
    const long row = blockIdx.x;
    f16* p = S + row * 2048;
    const int tid  = threadIdx.x;
    const int wave = tid >> 6;
    const int lane = tid & 63;

    f16x8 x = *(const f16x8*)&p[tid * 8];
    float v[8];
    float m = -1e30f;
    #pragma unroll
    for (int j = 0; j < 8; ++j) { v[j] = (float)x[j]; m = fmaxf(m, v[j]); }
    #pragma unroll
    for (int off = 32; off > 0; off >>= 1) m = fmaxf(m, __shfl_down(m, off));

    __shared__ float rm[4], rs[4];
    if (lane == 0) rm[wave] = m;
    __syncthreads();
    m = fmaxf(fmaxf(rm[0], rm[1]), fmaxf(rm[2], rm[3]));

    float s = 0.f;
    #pragma unroll
    for (int j = 0; j < 8; ++j) { v[j] = __expf(v[j] - m); s += v[j]; }
    #pragma unroll
    for (int off = 32; off > 0; off >>= 1) s += __shfl_down(s, off);
    if (lane == 0) rs[wave] = s;
    __syncthreads();
    s = rs[0] + rs[1] + rs[2] + rs[3];
    const float inv = 1.0f / s;

    f16x8 y;
    #pragma unroll
    for (int j = 0; j < 8; ++j) y[j] = (f16)(v[j] * inv);
    *(f16x8*)&p[tid * 8] = y;
}

// ---------------------------------------------------------------------------
// fused fp32 -> f16 convert: blocks [0,3072) do x (6.29M elems),
// blocks [3072, 4224) do the 4 weight matrices (589824 elems each).
// ---------------------------------------------------------------------------
__global__ __launch_bounds__(256)
void cvt_all_kernel(const float* __restrict__ x,
                    const float* __restrict__ w0, const float* __restrict__ w1,
                    const float* __restrict__ w2, const float* __restrict__ w3,
                    f16* __restrict__ x16, f16* __restrict__ w16)
{
    const float* in; f16* out; long i;
    if (blockIdx.x < 3072) {
        in = x; out = x16;
        i = ((long)blockIdx.x * 256 + threadIdx.x) * 8;
    } else {
        const int wb  = blockIdx.x - 3072;          // 0..1151
        const int sel = wb / 288;                   // 288 blocks per weight
        in  = (sel == 0) ? w0 : (sel == 1) ? w1 : (sel == 2) ? w2 : w3;
        out = w16 + (long)sel * 589824;
        i = ((long)(wb - sel * 288) * 256 + threadIdx.x) * 8;
    }
    float4 a = *(const float4*)(in + i);
    float4 b = *(const float4*)(in + i + 4);
    f16x8 o;
    o[0] = (f16)a.x; o[1] = (f16)a.y; o[2] = (f16)a.z; o[3] = (f16)a.w;
    o[4] = (f16)b.x; o[5] = (f16)b.y; o[6] = (f16)b.z; o[7] = (f16)b.w;
    *(f16x8*)&out[i] = o;
}

// ---------------------------------------------------------------------------
// B=4, S=2048, D=H=768.  ws layout (bytes):
//   x16 @0  (12.6MB) | w16 @12582912 (4.7MB: wq,wk,wv,wo) | Q @17301504
//   K @29884416 | VT @42467328 ([4][768][2048]) | S @55050240 (33.5MB)
//   Y @88604672      total ~101 MB
// ---------------------------------------------------------------------------
extern "C" void kernel_launch(void* const* d_in, const int* in_sizes, int n_in,
                              void* d_out, int out_size, void* d_ws, size_t ws_size,
                              hipStream_t stream)
{
    const float* x  = (const float*)d_in[0];
    const float* wq = (const float*)d_in[1];
    const float* bq = (const float*)d_in[2];
    const float* wk = (const float*)d_in[3];
    const float* bk = (const float*)d_in[4];
    const float* wv = (const float*)d_in[5];
    const float* bv = (const float*)d_in[6];
    const float* wo = (const float*)d_in[7];
    const float* bo = (const float*)d_in[8];

    char* ws = (char*)d_ws;
    f16* x16 = (f16*)(ws + 0);
    f16* w16 = (f16*)(ws + 12582912);
    f16* Q   = (f16*)(ws + 17301504);
    f16* Kb  = (f16*)(ws + 29884416);
    f16* VT  = (f16*)(ws + 42467328);
    f16* S   = (f16*)(ws + 55050240);
    f16* Y   = (f16*)(ws + 88604672);

    f16* wv16 = w16 + 2 * 589824;
    f16* wo16 = w16 + 3 * 589824;

    cvt_all_kernel<<<4224, 256, 0, stream>>>(x, wq, wk, wv, wo, x16, w16);

    // fused Q|K projection: B = [wq;wk], N=1536, split outputs (768 blocks)
    gemm_kernel<f16, 128, 128, 3, 3><<<dim3(64, 12, 1), 256, 0, stream>>>(
        x16, 0, w16, 0, Q, 0, Kb, bq, bk, 1536, 768);
    // VT[b][h][s] = sum_d wv[h][d] x[b][s][d] + bv[h]  (row-bias, coalesced
    // row-major VT writes; 768 blocks)
    gemm_kernel<f16, 64, 128, 2, 4><<<dim3(12, 16, 4), 256, 0, stream>>>(
        wv16, 0, x16, (long)2048 * 768, VT, (long)768 * 2048, nullptr,
        bv, nullptr, 2048, 768);
    // S[b] = Q[b] @ K[b]^T  (128x256 tiles, 512 blocks = 2/CU)
    gemm_kernel<f16, 128, 256, 0, 2><<<dim3(16, 8, 4), 256, 0, stream>>>(
        Q, (long)2048 * 768, Kb, (long)2048 * 768, S, (long)2048 * 2048,
        nullptr, nullptr, nullptr, 2048, 768);
    softmax_kernel<<<8192, 256, 0, stream>>>(S);
    // Y[b] = P[b] @ V[b]: A = S, B = VT  (128x128 tiles, 384 blocks, K=2048)
    gemm_kernel<f16, 128, 128, 0, 3><<<dim3(16, 6, 4), 256, 0, stream>>>(
        S, (long)2048 * 2048, VT, (long)768 * 2048, Y, (long)2048 * 768,
        nullptr, nullptr, nullptr, 768, 2048);
    // out = Y @ wo^T + bo (fp32 out, 128x128 tiles, 384 blocks)
    gemm_kernel<float, 128, 128, 1, 3><<<dim3(64, 6, 1), 256, 0, stream>>>(
        Y, 0, wo16, 0, (float*)d_out, 0, nullptr, bo, nullptr, 768, 768);
}

// Round 8
// 235.946 us; speedup vs baseline: 1.0768x; 1.0236x over previous
//
#include <hip/hip_runtime.h>

typedef _Float16 f16;
typedef _Float16 f16x8 __attribute__((ext_vector_type(8)));
typedef float f32x4 __attribute__((ext_vector_type(4)));

// async global->LDS, 16B per lane; LDS dest = wave-uniform base + lane*16
#define GLD16(g, l) __builtin_amdgcn_global_load_lds( \
    (const __attribute__((address_space(1))) void*)(g), \
    (__attribute__((address_space(3))) void*)(l), 16, 0, 0)

// ---------------------------------------------------------------------------
// Generic f16 MFMA GEMM, BK=64: C[m][n] = sum_k A[m][k]*B[n][k] (+bias)
// A: [M][K] f16 row-major, B: [N][K] f16 row-major (B^T layout).
// MODE: 0 none, 1 bias[col], 2 bias[row], 3 split-QK (col<768 -> C else C2).
// 256 threads = 4 waves (2x2); wave tile (BM/2)x(BN/2); MFMA 16x16x32_f16,
// two k-groups per K-step. Two-barrier single-buffer K-loop (graph-replay-
// safe; single-barrier dbuf raced in R3). LDS row = 64 f16 = 128 B; XOR
// swizzle: slot s of row r holds global chunk s^(r&7) -> ds_read_b128
// bank-conflict-free (R5/R6/R7: SQ_LDS_BANK_CONFLICT = 0).
// GRID SIZING (R7 lesson): per K-step, compute ~350 cyc vs load+drain
// ~600-900 cyc -> need >=3 blocks/CU resident to hide latency. Prefer
// smaller BM over bigger tiles whenever grid would drop below 768 blocks.
// Epilogues write row-major/coalesced only (R6: transposed epilogue cost
// +24 MB write amplification).
// ---------------------------------------------------------------------------
template <typename OutT, int BM, int BN, int MODE, int MINW>
__global__ __launch_bounds__(256, MINW)
void gemm_kernel(const f16* __restrict__ A, long sA,
                 const f16* __restrict__ B, long sB,
                 void* __restrict__ Cv, long sC,
                 void* __restrict__ C2v,
                 const float* __restrict__ bias,
                 const float* __restrict__ bias2,
                 int N, int K)
{
    constexpr int FM = BM / 32;   // A-frags per wave
    constexpr int FN = BN / 32;
    constexpr int IA = BM / 32;   // staging issues per wave (8 rows each)
    constexpr int IB = BN / 32;

    OutT* C  = (OutT*)Cv;
    OutT* C2 = (OutT*)C2v;
    const int tid  = threadIdx.x;
    const int wave = tid >> 6;
    const int lane = tid & 63;
    const int bz   = blockIdx.z;
    A += (long)bz * sA;
    B += (long)bz * sB;
    C += (long)bz * sC;
    const long bm = (long)blockIdx.x * BM;
    const long bn = (long)blockIdx.y * BN;

    __shared__ f16 sAt[BM * 64];
    __shared__ f16 sBt[BN * 64];

    // staging lane map: row = lane>>3, slot = lane&7, source chunk slot^row
    const int srow = lane >> 3;
    const int gch  = ((lane & 7) ^ srow) * 8;

    const f16* gAb = A + (bm + wave * (BM / 4) + srow) * (long)K + gch;
    const f16* gBb = B + (bn + wave * (BN / 4) + srow) * (long)K + gch;

    const int wm = (wave >> 1) * (BM / 2);
    const int wn = (wave & 1) * (BN / 2);
    const int lr = lane & 15;
    const int qd = lane >> 4;
    // reader swizzle per k-group h: slot = (h*4+qd) ^ (lr&7)
    const int swz0 = ((0 * 4 + qd) ^ (lr & 7)) * 8;
    const int swz1 = ((1 * 4 + qd) ^ (lr & 7)) * 8;

    f32x4 acc[FM][FN] = {};

    for (int k0 = 0; k0 < K; k0 += 64) {
        #pragma unroll
        for (int i = 0; i < IA; ++i)
            GLD16(gAb + k0 + (long)i * 8 * K, &sAt[(wave * (BM / 4) + i * 8) * 64]);
        #pragma unroll
        for (int i = 0; i < IB; ++i)
            GLD16(gBb + k0 + (long)i * 8 * K, &sBt[(wave * (BN / 4) + i * 8) * 64]);
        __syncthreads();

        #pragma unroll
        for (int h = 0; h < 2; ++h) {
            const int swz = h ? swz1 : swz0;
            f16x8 af[FM], bf[FN];
            #pragma unroll
            for (int t = 0; t < FM; ++t)
                af[t] = *(const f16x8*)&sAt[(wm + t * 16 + lr) * 64 + swz];
            #pragma unroll
            for (int t = 0; t < FN; ++t)
                bf[t] = *(const f16x8*)&sBt[(wn + t * 16 + lr) * 64 + swz];
            #pragma unroll
            for (int tm = 0; tm < FM; ++tm)
                #pragma unroll
                for (int tn = 0; tn < FN; ++tn)
                    acc[tm][tn] = __builtin_amdgcn_mfma_f32_16x16x32_f16(
                        af[tm], bf[tn], acc[tm][tn], 0, 0, 0);
        }
        __syncthreads();
    }

    // epilogue: C/D layout col = lane&15, row = (lane>>4)*4 + reg
    #pragma unroll
    for (int tn = 0; tn < FN; ++tn) {
        const long col = bn + wn + tn * 16 + lr;
        OutT* dst = C;
        long cc = col, stride = N;
        float bc = 0.f;
        if (MODE == 1) bc = bias[col];
        if (MODE == 3) {
            stride = 768;
            if (col >= 768) { dst = C2; cc = col - 768; bc = bias2[cc]; }
            else            { bc = bias[cc]; }
        }
        #pragma unroll
        for (int tm = 0; tm < FM; ++tm) {
            #pragma unroll
            for (int r = 0; r < 4; ++r) {
                const long row = bm + wm + tm * 16 + qd * 4 + r;
                float v = acc[tm][tn][r] + bc;
                if (MODE == 2) v += bias[row];
                dst[row * stride + cc] = (OutT)v;
            }
        }
    }
}

// ---------------------------------------------------------------------------
// In-place row softmax over f16 scores; one block per row of 2048.
// fp32 math, unscaled (faithful to reference). Proven in R1/R2/R5/R7.
// ---------------------------------------------------------------------------
__global__ __launch_bounds__(256)
void softmax_kernel(f16* __restrict__ S)
{
    const long row = blockIdx.x;
    f16* p = S + row * 2048;
    const int tid  = threadIdx.x;
    const int wave = tid >> 6;
    const int lane = tid & 63;

    f16x8 x = *(const f16x8*)&p[tid * 8];
    float v[8];
    float m = -1e30f;
    #pragma unroll
    for (int j = 0; j < 8; ++j) { v[j] = (float)x[j]; m = fmaxf(m, v[j]); }
    #pragma unroll
    for (int off = 32; off > 0; off >>= 1) m = fmaxf(m, __shfl_down(m, off));

    __shared__ float rm[4], rs[4];
    if (lane == 0) rm[wave] = m;
    __syncthreads();
    m = fmaxf(fmaxf(rm[0], rm[1]), fmaxf(rm[2], rm[3]));

    float s = 0.f;
    #pragma unroll
    for (int j = 0; j < 8; ++j) { v[j] = __expf(v[j] - m); s += v[j]; }
    #pragma unroll
    for (int off = 32; off > 0; off >>= 1) s += __shfl_down(s, off);
    if (lane == 0) rs[wave] = s;
    __syncthreads();
    s = rs[0] + rs[1] + rs[2] + rs[3];
    const float inv = 1.0f / s;

    f16x8 y;
    #pragma unroll
    for (int j = 0; j < 8; ++j) y[j] = (f16)(v[j] * inv);
    *(f16x8*)&p[tid * 8] = y;
}

// ---------------------------------------------------------------------------
// fused fp32 -> f16 convert: blocks [0,3072) do x (6.29M elems),
// blocks [3072, 4224) do the 4 weight matrices (589824 elems each).
// ---------------------------------------------------------------------------
__global__ __launch_bounds__(256)
void cvt_all_kernel(const float* __restrict__ x,
                    const float* __restrict__ w0, const float* __restrict__ w1,
                    const float* __restrict__ w2, const float* __restrict__ w3,
                    f16* __restrict__ x16, f16* __restrict__ w16)
{
    const float* in; f16* out; long i;
    if (blockIdx.x < 3072) {
        in = x; out = x16;
        i = ((long)blockIdx.x * 256 + threadIdx.x) * 8;
    } else {
        const int wb  = blockIdx.x - 3072;          // 0..1151
        const int sel = wb / 288;                   // 288 blocks per weight
        in  = (sel == 0) ? w0 : (sel == 1) ? w1 : (sel == 2) ? w2 : w3;
        out = w16 + (long)sel * 589824;
        i = ((long)(wb - sel * 288) * 256 + threadIdx.x) * 8;
    }
    float4 a = *(const float4*)(in + i);
    float4 b = *(const float4*)(in + i + 4);
    f16x8 o;
    o[0] = (f16)a.x; o[1] = (f16)a.y; o[2] = (f16)a.z; o[3] = (f16)a.w;
    o[4] = (f16)b.x; o[5] = (f16)b.y; o[6] = (f16)b.z; o[7] = (f16)b.w;
    *(f16x8*)&out[i] = o;
}

// ---------------------------------------------------------------------------
// B=4, S=2048, D=H=768.  ws layout (bytes):
//   x16 @0  (12.6MB) | w16 @12582912 (4.7MB: wq,wk,wv,wo) | Q @17301504
//   K @29884416 | VT @42467328 ([4][768][2048]) | S @55050240 (33.5MB)
//   Y @88604672      total ~101 MB
// ---------------------------------------------------------------------------
extern "C" void kernel_launch(void* const* d_in, const int* in_sizes, int n_in,
                              void* d_out, int out_size, void* d_ws, size_t ws_size,
                              hipStream_t stream)
{
    const float* x  = (const float*)d_in[0];
    const float* wq = (const float*)d_in[1];
    const float* bq = (const float*)d_in[2];
    const float* wk = (const float*)d_in[3];
    const float* bk = (const float*)d_in[4];
    const float* wv = (const float*)d_in[5];
    const float* bv = (const float*)d_in[6];
    const float* wo = (const float*)d_in[7];
    const float* bo = (const float*)d_in[8];

    char* ws = (char*)d_ws;
    f16* x16 = (f16*)(ws + 0);
    f16* w16 = (f16*)(ws + 12582912);
    f16* Q   = (f16*)(ws + 17301504);
    f16* Kb  = (f16*)(ws + 29884416);
    f16* VT  = (f16*)(ws + 42467328);
    f16* S   = (f16*)(ws + 55050240);
    f16* Y   = (f16*)(ws + 88604672);

    f16* wv16 = w16 + 2 * 589824;
    f16* wo16 = w16 + 3 * 589824;

    cvt_all_kernel<<<4224, 256, 0, stream>>>(x, wq, wk, wv, wo, x16, w16);

    // fused Q|K projection: B = [wq;wk], N=1536, split outputs
    // (768 blocks = 3/CU)
    gemm_kernel<f16, 128, 128, 3, 3><<<dim3(64, 12, 1), 256, 0, stream>>>(
        x16, 0, w16, 0, Q, 0, Kb, bq, bk, 1536, 768);
    // VT[b][h][s] = sum_d wv[h][d] x[b][s][d] + bv[h]  (row-bias, coalesced
    // row-major VT writes; 768 blocks = 3/CU)
    gemm_kernel<f16, 64, 128, 2, 4><<<dim3(12, 16, 4), 256, 0, stream>>>(
        wv16, 0, x16, (long)2048 * 768, VT, (long)768 * 2048, nullptr,
        bv, nullptr, 2048, 768);
    // S[b] = Q[b] @ K[b]^T  (128x128 tiles, 1024 blocks = 4/CU)
    gemm_kernel<f16, 128, 128, 0, 3><<<dim3(16, 16, 4), 256, 0, stream>>>(
        Q, (long)2048 * 768, Kb, (long)2048 * 768, S, (long)2048 * 2048,
        nullptr, nullptr, nullptr, 2048, 768);
    softmax_kernel<<<8192, 256, 0, stream>>>(S);
    // Y[b] = P[b] @ V[b]: A = S, B = VT  (64x128 tiles, 768 blocks = 3/CU)
    gemm_kernel<f16, 64, 128, 0, 4><<<dim3(32, 6, 4), 256, 0, stream>>>(
        S, (long)2048 * 2048, VT, (long)768 * 2048, Y, (long)2048 * 768,
        nullptr, nullptr, nullptr, 768, 2048);
    // out = Y @ wo^T + bo (fp32 out, 64x128 tiles, 768 blocks = 3/CU)
    gemm_kernel<float, 64, 128, 1, 4><<<dim3(128, 6, 1), 256, 0, stream>>>(
        Y, 0, wo16, 0, (float*)d_out, 0, nullptr, bo, nullptr, 768, 768);
}

// Round 9
// 231.979 us; speedup vs baseline: 1.0952x; 1.0171x over previous
//
#include <hip/hip_runtime.h>

typedef _Float16 f16;
typedef _Float16 f16x8 __attribute__((ext_vector_type(8)));
typedef float f32x4 __attribute__((ext_vector_type(4)));

// async global->LDS, 16B per lane; LDS dest = wave-uniform base + lane*16
#define GLD16(g, l) __builtin_amdgcn_global_load_lds( \
    (const __attribute__((address_space(1))) void*)(g), \
    (__attribute__((address_space(3))) void*)(l), 16, 0, 0)

// compiler memory fence: forbids moving the GLD16 issue block across
// barriers (global_load_lds's LDS write is not modeled by the compiler;
// R3's race is attributed to hoisting across __syncthreads).
#define MEMFENCE asm volatile("" ::: "memory")

// ---------------------------------------------------------------------------
// Generic f16 MFMA GEMM, BK=64: C[m][n] = sum_k A[m][k]*B[n][k] (+bias)
// A: [M][K] f16 row-major, B: [N][K] f16 row-major (B^T layout).
// MODE: 0 none, 1 bias[col], 2 bias[row], 3 split-QK (col<768 -> C else C2).
// DBUF=0: proven two-barrier single-buffer K-loop (R1..R8 graph-replay-safe).
// DBUF=1: double-buffered prefetch, one barrier/step + prologue barrier:
//   issue L(0); barrier; for s: { [fence] issue L(s+1)->buf[(s+1)&1] [fence];
//   compute buf[s&1]; barrier }
//   Safety: compiler emits vmcnt(0) before s_barrier (proven by R5-R8
//   correctness), so L(s) is drained at the barrier ending step s-1; buffer
//   parity reuse is barrier-separated; fences pin the issue block.
// LDS row = 64 f16 = 128 B; XOR swizzle: slot s of row r holds global chunk
// s^(r&7) -> ds_read_b128 bank-conflict-free (R5-R8: SQ_LDS_BANK_CONFLICT=0).
// GRID SIZING (R7/R8 lesson): need >=3 blocks/CU; R5 shapes are empirical
// best (scores 128x256, PV/out 128x64). Epilogues row-major/coalesced only
// (R6: transposed epilogue cost +24 MB write amplification).
// ---------------------------------------------------------------------------
template <typename OutT, int BM, int BN, int MODE, int MINW, int DBUF>
__global__ __launch_bounds__(256, MINW)
void gemm_kernel(const f16* __restrict__ A, long sA,
                 const f16* __restrict__ B, long sB,
                 void* __restrict__ Cv, long sC,
                 void* __restrict__ C2v,
                 const float* __restrict__ bias,
                 const float* __restrict__ bias2,
                 int N, int K)
{
    constexpr int FM = BM / 32;   // A-frags per wave
    constexpr int FN = BN / 32;
    constexpr int IA = BM / 32;   // staging issues per wave (8 rows each)
    constexpr int IB = BN / 32;

    OutT* C  = (OutT*)Cv;
    OutT* C2 = (OutT*)C2v;
    const int tid  = threadIdx.x;
    const int wave = tid >> 6;
    const int lane = tid & 63;
    const int bz   = blockIdx.z;
    A += (long)bz * sA;
    B += (long)bz * sB;
    C += (long)bz * sC;
    const long bm = (long)blockIdx.x * BM;
    const long bn = (long)blockIdx.y * BN;

    __shared__ f16 sAt[(DBUF + 1) * BM * 64];
    __shared__ f16 sBt[(DBUF + 1) * BN * 64];

    // staging lane map: row = lane>>3, slot = lane&7, source chunk slot^row
    const int srow = lane >> 3;
    const int gch  = ((lane & 7) ^ srow) * 8;

    const f16* gAb = A + (bm + wave * (BM / 4) + srow) * (long)K + gch;
    const f16* gBb = B + (bn + wave * (BN / 4) + srow) * (long)K + gch;

    const int wm = (wave >> 1) * (BM / 2);
    const int wn = (wave & 1) * (BN / 2);
    const int lr = lane & 15;
    const int qd = lane >> 4;
    // reader swizzle per k-group h: slot = (h*4+qd) ^ (lr&7)
    const int swz0 = ((0 * 4 + qd) ^ (lr & 7)) * 8;
    const int swz1 = ((1 * 4 + qd) ^ (lr & 7)) * 8;

    f32x4 acc[FM][FN] = {};

    auto issue = [&](int k0, int b) {
        f16* dA = &sAt[b * BM * 64];
        f16* dB = &sBt[b * BN * 64];
        #pragma unroll
        for (int i = 0; i < IA; ++i)
            GLD16(gAb + k0 + (long)i * 8 * K, &dA[(wave * (BM / 4) + i * 8) * 64]);
        #pragma unroll
        for (int i = 0; i < IB; ++i)
            GLD16(gBb + k0 + (long)i * 8 * K, &dB[(wave * (BN / 4) + i * 8) * 64]);
    };

    auto compute = [&](int b) {
        const f16* dA = &sAt[b * BM * 64];
        const f16* dB = &sBt[b * BN * 64];
        #pragma unroll
        for (int h = 0; h < 2; ++h) {
            const int swz = h ? swz1 : swz0;
            f16x8 af[FM], bf[FN];
            #pragma unroll
            for (int t = 0; t < FM; ++t)
                af[t] = *(const f16x8*)&dA[(wm + t * 16 + lr) * 64 + swz];
            #pragma unroll
            for (int t = 0; t < FN; ++t)
                bf[t] = *(const f16x8*)&dB[(wn + t * 16 + lr) * 64 + swz];
            #pragma unroll
            for (int tm = 0; tm < FM; ++tm)
                #pragma unroll
                for (int tn = 0; tn < FN; ++tn)
                    acc[tm][tn] = __builtin_amdgcn_mfma_f32_16x16x32_f16(
                        af[tm], bf[tn], acc[tm][tn], 0, 0, 0);
        }
    };

    if (DBUF) {
        const int NS = K >> 6;
        issue(0, 0);
        __syncthreads();                      // L(0) drained (vmcnt0 @ barrier)
        for (int s = 0; s < NS; ++s) {
            MEMFENCE;
            if (s + 1 < NS) issue((s + 1) * 64, (s + 1) & 1);
            MEMFENCE;
            compute(s & 1);
            __syncthreads();                  // drains L(s+1); frees buf[s&1]
        }
    } else {
        for (int k0 = 0; k0 < K; k0 += 64) {
            issue(k0, 0);
            __syncthreads();
            compute(0);
            __syncthreads();
        }
    }

    // epilogue: C/D layout col = lane&15, row = (lane>>4)*4 + reg
    #pragma unroll
    for (int tn = 0; tn < FN; ++tn) {
        const long col = bn + wn + tn * 16 + lr;
        OutT* dst = C;
        long cc = col, stride = N;
        float bc = 0.f;
        if (MODE == 1) bc = bias[col];
        if (MODE == 3) {
            stride = 768;
            if (col >= 768) { dst = C2; cc = col - 768; bc = bias2[cc]; }
            else            { bc = bias[cc]; }
        }
        #pragma unroll
        for (int tm = 0; tm < FM; ++tm) {
            #pragma unroll
            for (int r = 0; r < 4; ++r) {
                const long row = bm + wm + tm * 16 + qd * 4 + r;
                float v = acc[tm][tn][r] + bc;
                if (MODE == 2) v += bias[row];
                dst[row * stride + cc] = (OutT)v;
            }
        }
    }
}

// ---------------------------------------------------------------------------
// In-place row softmax over f16 scores; one block per row of 2048.
// fp32 math, unscaled (faithful to reference). Proven R1..R8.
// ---------------------------------------------------------------------------
__global__ __launch_bounds__(256)
void softmax_kernel(f16* __restrict__ S)
{
    const long row = blockIdx.x;
    f16* p = S + row * 2048;
    const int tid  = threadIdx.x;
    const int wave = tid >> 6;
    const int lane = tid & 63;

    f16x8 x = *(const f16x8*)&p[tid * 8];
    float v[8];
    float m = -1e30f;
    #pragma unroll
    for (int j = 0; j < 8; ++j) { v[j] = (float)x[j]; m = fmaxf(m, v[j]); }
    #pragma unroll
    for (int off = 32; off > 0; off >>= 1) m = fmaxf(m, __shfl_down(m, off));

    __shared__ float rm[4], rs[4];
    if (lane == 0) rm[wave] = m;
    __syncthreads();
    m = fmaxf(fmaxf(rm[0], rm[1]), fmaxf(rm[2], rm[3]));

    float s = 0.f;
    #pragma unroll
    for (int j = 0; j < 8; ++j) { v[j] = __expf(v[j] - m); s += v[j]; }
    #pragma unroll
    for (int off = 32; off > 0; off >>= 1) s += __shfl_down(s, off);
    if (lane == 0) rs[wave] = s;
    __syncthreads();
    s = rs[0] + rs[1] + rs[2] + rs[3];
    const float inv = 1.0f / s;

    f16x8 y;
    #pragma unroll
    for (int j = 0; j < 8; ++j) y[j] = (f16)(v[j] * inv);
    *(f16x8*)&p[tid * 8] = y;
}

// ---------------------------------------------------------------------------
// fused fp32 -> f16 convert: blocks [0,3072) do x (6.29M elems),
// blocks [3072, 4224) do the 4 weight matrices (589824 elems each).
// ---------------------------------------------------------------------------
__global__ __launch_bounds__(256)
void cvt_all_kernel(const float* __restrict__ x,
                    const float* __restrict__ w0, const float* __restrict__ w1,
                    const float* __restrict__ w2, const float* __restrict__ w3,
                    f16* __restrict__ x16, f16* __restrict__ w16)
{
    const float* in; f16* out; long i;
    if (blockIdx.x < 3072) {
        in = x; out = x16;
        i = ((long)blockIdx.x * 256 + threadIdx.x) * 8;
    } else {
        const int wb  = blockIdx.x - 3072;          // 0..1151
        const int sel = wb / 288;                   // 288 blocks per weight
        in  = (sel == 0) ? w0 : (sel == 1) ? w1 : (sel == 2) ? w2 : w3;
        out = w16 + (long)sel * 589824;
        i = ((long)(wb - sel * 288) * 256 + threadIdx.x) * 8;
    }
    float4 a = *(const float4*)(in + i);
    float4 b = *(const float4*)(in + i + 4);
    f16x8 o;
    o[0] = (f16)a.x; o[1] = (f16)a.y; o[2] = (f16)a.z; o[3] = (f16)a.w;
    o[4] = (f16)b.x; o[5] = (f16)b.y; o[6] = (f16)b.z; o[7] = (f16)b.w;
    *(f16x8*)&out[i] = o;
}

// ---------------------------------------------------------------------------
// B=4, S=2048, D=H=768.  ws layout (bytes):
//   x16 @0  (12.6MB) | w16 @12582912 (4.7MB: wq,wk,wv,wo) | Q @17301504
//   K @29884416 | VT @42467328 ([4][768][2048]) | S @55050240 (33.5MB)
//   Y @88604672      total ~101 MB
// ---------------------------------------------------------------------------
extern "C" void kernel_launch(void* const* d_in, const int* in_sizes, int n_in,
                              void* d_out, int out_size, void* d_ws, size_t ws_size,
                              hipStream_t stream)
{
    const float* x  = (const float*)d_in[0];
    const float* wq = (const float*)d_in[1];
    const float* bq = (const float*)d_in[2];
    const float* wk = (const float*)d_in[3];
    const float* bk = (const float*)d_in[4];
    const float* wv = (const float*)d_in[5];
    const float* bv = (const float*)d_in[6];
    const float* wo = (const float*)d_in[7];
    const float* bo = (const float*)d_in[8];

    char* ws = (char*)d_ws;
    f16* x16 = (f16*)(ws + 0);
    f16* w16 = (f16*)(ws + 12582912);
    f16* Q   = (f16*)(ws + 17301504);
    f16* Kb  = (f16*)(ws + 29884416);
    f16* VT  = (f16*)(ws + 42467328);
    f16* S   = (f16*)(ws + 55050240);
    f16* Y   = (f16*)(ws + 88604672);

    f16* wv16 = w16 + 2 * 589824;
    f16* wo16 = w16 + 3 * 589824;

    cvt_all_kernel<<<4224, 256, 0, stream>>>(x, wq, wk, wv, wo, x16, w16);

    // fused Q|K projection: B = [wq;wk], N=1536 (768 blocks, single-buffer)
    gemm_kernel<f16, 128, 128, 3, 3, 0><<<dim3(64, 12, 1), 256, 0, stream>>>(
        x16, 0, w16, 0, Q, 0, Kb, bq, bk, 1536, 768);
    // VT[b][h][s] = sum_d wv[h][d] x[b][s][d] + bv[h]  (row-bias, dbuf,
    // 48KB LDS -> 3/CU, 768 blocks)
    gemm_kernel<f16, 64, 128, 2, 3, 1><<<dim3(12, 16, 4), 256, 0, stream>>>(
        wv16, 0, x16, (long)2048 * 768, VT, (long)768 * 2048, nullptr,
        bv, nullptr, 2048, 768);
    // S[b] = Q[b] @ K[b]^T  (128x256 single-buffer, 512 blocks — R5 best)
    gemm_kernel<f16, 128, 256, 0, 2, 0><<<dim3(16, 8, 4), 256, 0, stream>>>(
        Q, (long)2048 * 768, Kb, (long)2048 * 768, S, (long)2048 * 2048,
        nullptr, nullptr, nullptr, 2048, 768);
    softmax_kernel<<<8192, 256, 0, stream>>>(S);
    // Y[b] = P[b] @ V[b]: A = S, B = VT (128x64 dbuf, 768 blocks, K=2048)
    gemm_kernel<f16, 128, 64, 0, 3, 1><<<dim3(16, 12, 4), 256, 0, stream>>>(
        S, (long)2048 * 2048, VT, (long)768 * 2048, Y, (long)2048 * 768,
        nullptr, nullptr, nullptr, 768, 2048);
    // out = Y @ wo^T + bo (fp32 out, 128x64 dbuf, 768 blocks)
    gemm_kernel<float, 128, 64, 1, 3, 1><<<dim3(64, 12, 1), 256, 0, stream>>>(
        Y, 0, wo16, 0, (float*)d_out, 0, nullptr, bo, nullptr, 768, 768);
}